// Round 3
// baseline (253.854 us; speedup 1.0000x reference)
//
#include <hip/hip_runtime.h>
#include <hip/hip_bf16.h>
#include <math.h>

// Problem: MultiHeadSelfAttention  B=4, S=2048, D=1024, H=16, Hd=64
// fp32 in / fp32 out. bf16 scratch, fp32 accumulation.
// Round 12:
//  - gemm: unchanged from R11 (counted-vmcnt ring-3, 256x128, 8 waves).
//  - attn: swapped QK^T (mfma(K,Q) -> lane-local q-rows; identical LDS
//    reads, S^T output). P pack via v_perm pairs + 4x ds_write_b64
//    (conflict-free) replaces 16x ds_write_u16 @4-way (9.5M conflicts).
//    Scalar l accumulator + xor16/32 reduce. T14 async-stage: K/V tile
//    jt+1 global->reg issued before compute jt, reg->LDS after barrier.
//    T5 setprio around MFMA clusters. V-pack via v_perm.
// ws: Qb@0, Kb@16M, Vb@32M, Xb/Ob@48M (aliased). Wstash in d_out (dead
// until final GEMM); wo converted into Qb after attention frees it.

#define S_LEN 2048
#define DM    1024
#define NH    16
#define HD    64
#define M_ROWS 8192   // B * S

typedef __attribute__((ext_vector_type(8))) short bf16x8;
typedef __attribute__((ext_vector_type(4))) float f32x4;

__device__ __forceinline__ float bf2f(unsigned short u) {
  union { unsigned int i; float f; } c; c.i = ((unsigned int)u) << 16; return c.f;
}
__device__ __forceinline__ unsigned short f2bf(float f) {
  unsigned int x = __float_as_uint(f);
  if ((x & 0x7fffffffu) > 0x7f800000u) return (unsigned short)0x7fc0u;  // NaN
  return (unsigned short)((x + 0x7fffu + ((x >> 16) & 1u)) >> 16);      // RNE
}
// async global->LDS, 16 B per lane; lds dest must be wave-uniform
__device__ __forceinline__ void gl_lds16(const unsigned short* g, unsigned short* l) {
  __builtin_amdgcn_global_load_lds(
      (const __attribute__((address_space(1))) unsigned int*)g,
      (__attribute__((address_space(3))) unsigned int*)l, 16, 0, 0);
}

#define FENCE() asm volatile("" ::: "memory")

// ---------------------------------------------------------------------------
// fp32 -> bf16 bulk convert (8 elems/thread)
// ---------------------------------------------------------------------------
__global__ __launch_bounds__(256) void cvt_bf16(const float* __restrict__ in,
                                                unsigned short* __restrict__ out) {
  const int i = blockIdx.x * 256 + threadIdx.x;
  float4 a = ((const float4*)in)[2 * i];
  float4 b = ((const float4*)in)[2 * i + 1];
  ushort4 r0, r1;
  r0.x = f2bf(a.x); r0.y = f2bf(a.y); r0.z = f2bf(a.z); r0.w = f2bf(a.w);
  r1.x = f2bf(b.x); r1.y = f2bf(b.y); r1.z = f2bf(b.z); r1.w = f2bf(b.w);
  ((ushort4*)out)[2 * i] = r0;
  ((ushort4*)out)[2 * i + 1] = r1;
}

// convert wq,wk,wv (1M fp32 each) into one contiguous bf16 stash [3072][1024]
__global__ __launch_bounds__(256) void cvt_w3(const float* __restrict__ w0,
                                              const float* __restrict__ w1,
                                              const float* __restrict__ w2,
                                              unsigned short* __restrict__ out) {
  const int idx = blockIdx.x;                 // 0..1535
  const int which = idx >> 9;
  const float* src = (which == 0) ? w0 : (which == 1) ? w1 : w2;
  unsigned short* dst = out + (size_t)which * (DM * DM);
  const int i = (idx & 511) * 256 + threadIdx.x;
  float4 a = ((const float4*)src)[2 * i];
  float4 b = ((const float4*)src)[2 * i + 1];
  ushort4 r0, r1;
  r0.x = f2bf(a.x); r0.y = f2bf(a.y); r0.z = f2bf(a.z); r0.w = f2bf(a.w);
  r1.x = f2bf(b.x); r1.y = f2bf(b.y); r1.z = f2bf(b.z); r1.w = f2bf(b.w);
  ((ushort4*)dst)[2 * i] = r0;
  ((ushort4*)dst)[2 * i + 1] = r1;
}

// ---------------------------------------------------------------------------
// MFMA GEMM, counted-vmcnt ring-3 global_load_lds pipeline (R11, verified).
// ---------------------------------------------------------------------------
template <int OUT_MODE>
__global__ __launch_bounds__(512, 4) void gemm_bt(const unsigned short* __restrict__ A,
                                                  const unsigned short* __restrict__ Wall,
                                                  unsigned short* __restrict__ outB,
                                                  float* __restrict__ outF) {
  __shared__ __align__(16) unsigned short As[3 * 8192];  // [buf][kgrp4][256][8]
  __shared__ __align__(16) unsigned short Bs[3 * 4096];  // [buf][kgrp4][128][8]
  const int m0 = blockIdx.x * 256;
  const int n0 = blockIdx.y * 128;
  const int tid = threadIdx.x;
  const int lane = tid & 63, w = tid >> 6;
  const int quad = lane >> 4, l15 = lane & 15;
  const int wrow = w >> 1, wcol = w & 1;    // compute mapping: 4M x 2N waves

  // staging map (independent of compute mapping)
  const int skg = w & 3, srq = w >> 2;
  const unsigned short* agA = A    + (size_t)(m0 + srq * 64 + lane) * DM + skg * 8;
  const unsigned short* bgB = Wall + (size_t)(n0 + srq * 64 + lane) * DM + skg * 8;
  const int lA0 = skg * 2048 + srq * 512;   // wave-uniform LDS elem offsets
  const int lA1 = lA0 + 1024;               // rows +128
  const int lB  = skg * 1024 + srq * 512;
  const int raA = quad * 2048 + (wrow * 64 + l15) * 8;  // frag-read bases
  const int raB = quad * 1024 + (wcol * 64 + l15) * 8;

  f32x4 acc[4][4];
#pragma unroll
  for (int i = 0; i < 4; ++i)
#pragma unroll
    for (int j = 0; j < 4; ++j) { acc[i][j].x = 0.f; acc[i][j].y = 0.f; acc[i][j].z = 0.f; acc[i][j].w = 0.f; }

#define STAGE3(T, SB) do {                                                   \
    const unsigned short* ap_ = agA + (size_t)(T) * 32;                      \
    gl_lds16(ap_,          &As[(SB) * 8192 + lA0]);                          \
    gl_lds16(ap_ + 131072, &As[(SB) * 8192 + lA1]);                          \
    gl_lds16(bgB + (size_t)(T) * 32, &Bs[(SB) * 4096 + lB]);                 \
  } while (0)

#define COMPUTE(CB) do {                                                     \
    bf16x8 af_[4], bq_[4];                                                   \
    _Pragma("unroll")                                                        \
    for (int mi = 0; mi < 4; ++mi)                                           \
      af_[mi] = *(const bf16x8*)&As[(CB) * 8192 + raA + mi * 128];           \
    _Pragma("unroll")                                                        \
    for (int ni = 0; ni < 4; ++ni)                                           \
      bq_[ni] = *(const bf16x8*)&Bs[(CB) * 4096 + raB + ni * 128];           \
    __builtin_amdgcn_s_setprio(1);                                           \
    _Pragma("unroll")                                                        \
    for (int mi = 0; mi < 4; ++mi)                                           \
      _Pragma("unroll")                                                      \
      for (int ni = 0; ni < 4; ++ni)                                         \
        acc[mi][ni] = __builtin_amdgcn_mfma_f32_16x16x32_bf16(af_[mi], bq_[ni], acc[mi][ni], 0, 0, 0); \
    __builtin_amdgcn_s_setprio(0);                                           \
  } while (0)

#define SUBSTEP(T, SB, CB) do {                                              \
    FENCE();                                                                 \
    STAGE3((T), (SB));                                                       \
    asm volatile("s_waitcnt vmcnt(6)" ::: "memory");                         \
    __builtin_amdgcn_s_barrier();                                            \
    FENCE();                                                                 \
    COMPUTE(CB);                                                             \
    FENCE();                                                                 \
    __builtin_amdgcn_s_barrier();                                            \
  } while (0)

  // prologue: tiles 0,1 into bufs 0,1 (ring fills; no wait yet)
  STAGE3(0, 0);
  STAGE3(1, 1);

  // main loop: 30 tiles, unrolled x3 for compile-time buffer indices
  for (int t = 0; t < 30; t += 3) {
    SUBSTEP(t + 2, 2, 0);
    SUBSTEP(t + 3, 0, 1);
    SUBSTEP(t + 4, 1, 2);
  }
  // drain: tile 30 in buf0 (tile 31 still in flight), then tile 31 in buf1
  asm volatile("s_waitcnt vmcnt(3)" ::: "memory");
  __builtin_amdgcn_s_barrier();
  FENCE();
  COMPUTE(0);
  FENCE();
  __builtin_amdgcn_s_barrier();
  asm volatile("s_waitcnt vmcnt(0)" ::: "memory");
  __builtin_amdgcn_s_barrier();
  FENCE();
  COMPUTE(1);

#undef SUBSTEP
#undef COMPUTE
#undef STAGE3

  const float oscale = (OUT_MODE == 0 && n0 < 1024) ? 0.125f : 1.0f;
#pragma unroll
  for (int mi = 0; mi < 4; ++mi) {
#pragma unroll
    for (int reg = 0; reg < 4; ++reg) {
      const int m = m0 + wrow * 64 + mi * 16 + quad * 4 + reg;
#pragma unroll
      for (int ni = 0; ni < 4; ++ni) {
        const int e = n0 + wcol * 64 + ni * 16 + l15;
        const float v = acc[mi][ni][reg];
        if (OUT_MODE == 0) {
          const int z = e >> 10;                   // 0:Q 1:K 2:V
          const int e10 = e & 1023;
          const int b = m >> 11, s = m & (S_LEN - 1);
          const int h = e10 >> 6, hd = e10 & 63;
          outB[(size_t)z * (M_ROWS * DM) +
               (((size_t)(b * NH + h)) * S_LEN + s) * HD + hd] = f2bf(v * oscale);
        } else {
          outF[(size_t)m * DM + e] = v;
        }
      }
    }
  }
}

// ---------------------------------------------------------------------------
// MFMA flash attention, fixed-reference softmax, SWAPPED QK^T.
// mfma(K_frag, Q_frag) -> S^T: lane (quad,l15) holds S[k][q] with q = l15,
// k = sub*16 + quad*4 + reg.  Softmax row (fixed q) is split across quads:
// scalar l_acc per lane, xor16/32 reduce at epilogue.  P written as packed
// bf16 pairs (v_perm trunc) via ds_write_b64 into Pl[q][k] row-major --
// the PV A-operand read (Pl[l15][st*32+quad*8], b128) is unchanged.
// T14: K/V tile jt+1 global->reg before compute jt; reg->LDS next iter.
// 4 waves x 16 Q-rows; grid (bh=64, t=16), bx = t then 31-t (balanced).
// ---------------------------------------------------------------------------
__global__ __launch_bounds__(256) void attn_mfma(const unsigned short* __restrict__ Q,
                                                 const unsigned short* __restrict__ K,
                                                 const unsigned short* __restrict__ V,
                                                 unsigned short* __restrict__ O) {
  __shared__ unsigned short Ks[64][72];
  __shared__ unsigned short Vt[64][72];
  __shared__ unsigned short Pl[4][16][72];
  const int bh  = blockIdx.x;   // 0..63
  const int t   = blockIdx.y;   // 0..15
  const int tid = threadIdx.x;
  const int w    = tid >> 6;
  const int lane = tid & 63;
  const int quad = lane >> 4;
  const int l15  = lane & 15;

  const size_t base = (size_t)bh * S_LEN * HD;
  const int kr0 = tid >> 3, kc0 = (tid & 7) * 8;
  const int vs = (tid & 31) * 2, vh = (tid >> 5) * 8;
  const int b = bh >> 4, h = bh & 15;

  for (int phase = 0; phase < 2; ++phase) {
    const int bx  = phase ? (31 - t) : t;   // Q-block of 64 rows
    const int wq0 = bx * 64 + w * 16;
    const int qrow = wq0 + l15;             // this lane's q-row (swapped)

    bf16x8 qa[2];
#pragma unroll
    for (int st = 0; st < 2; ++st)
      qa[st] = *(const bf16x8*)(Q + base + (size_t)(wq0 + l15) * HD + st * 32 + quad * 8);

    f32x4 o[4];
#pragma unroll
    for (int sub = 0; sub < 4; ++sub) { o[sub].x = 0.f; o[sub].y = 0.f; o[sub].z = 0.f; o[sub].w = 0.f; }
    float l_acc = 0.f;

    const int jtmax = bx;

    // T14 preload: tile 0 -> regs
    uint4 krA, krB, vrA, vrB;
    {
      const unsigned short* kbp = K + base;
      const unsigned short* vbp = V + base;
      krA = *(const uint4*)(kbp + kr0 * HD + kc0);
      krB = *(const uint4*)(kbp + (kr0 + 32) * HD + kc0);
      vrA = *(const uint4*)(vbp + (size_t)vs * HD + vh);
      vrB = *(const uint4*)(vbp + (size_t)(vs + 1) * HD + vh);
    }

    for (int jt = 0; jt <= jtmax; ++jt) {
      __syncthreads();   // all waves done reading prev tile's LDS
      *(uint4*)&Ks[kr0][kc0]      = krA;
      *(uint4*)&Ks[kr0 + 32][kc0] = krB;
      {
        const unsigned int* a0 = (const unsigned int*)&vrA;
        const unsigned int* a1 = (const unsigned int*)&vrB;
#pragma unroll
        for (int i = 0; i < 4; ++i) {
          *(unsigned int*)&Vt[vh + 2 * i][vs]     = __builtin_amdgcn_perm(a1[i], a0[i], 0x05040100u);
          *(unsigned int*)&Vt[vh + 2 * i + 1][vs] = __builtin_amdgcn_perm(a1[i], a0[i], 0x07060302u);
        }
      }
      __syncthreads();

      // issue next tile's loads now; first use is next iteration's LDS write,
      // so the latency hides under this tile's QK/softmax/PV
      if (jt < jtmax) {
        const unsigned short* kbp = K + base + (size_t)(jt + 1) * 64 * HD;
        const unsigned short* vbp = V + base + (size_t)(jt + 1) * 64 * HD;
        krA = *(const uint4*)(kbp + kr0 * HD + kc0);
        krB = *(const uint4*)(kbp + (kr0 + 32) * HD + kc0);
        vrA = *(const uint4*)(vbp + (size_t)vs * HD + vh);
        vrB = *(const uint4*)(vbp + (size_t)(vs + 1) * HD + vh);
      }

      const int rel = jt * 64 - wq0;     // wave-uniform, <= 0
      const bool partial = (rel >= -63); // only the jt == bx tile
      const int submax = partial ? (((15 - rel) >> 4) + 1) : 4;
      const int steps  = partial ? ((submax + 1) >> 1) : 2;

      // swapped QK^T: ST = K_tile . Q^T  (same LDS reads as unswapped)
      f32x4 s[4];
      __builtin_amdgcn_s_setprio(1);
#pragma unroll
      for (int sub = 0; sub < 4; ++sub) {
        if (sub < submax) {
          bf16x8 kb0 = *(const bf16x8*)&Ks[sub * 16 + l15][quad * 8];
          bf16x8 kb1 = *(const bf16x8*)&Ks[sub * 16 + l15][quad * 8 + 32];
          f32x4 acc = {0.f, 0.f, 0.f, 0.f};
          acc = __builtin_amdgcn_mfma_f32_16x16x32_bf16(kb0, qa[0], acc, 0, 0, 0);
          acc = __builtin_amdgcn_mfma_f32_16x16x32_bf16(kb1, qa[1], acc, 0, 0, 0);
          s[sub] = acc;
        }
      }
      __builtin_amdgcn_s_setprio(0);

      // fixed-reference softmax on lane-local q-row slices; pack pairs and
      // write 8B per sub (conflict-free) into Pl[q=l15][k]
#pragma unroll
      for (int sub = 0; sub < 4; ++sub) {
        if (sub < submax) {
          float p0, p1, p2, p3;
          {
            float v0 = s[sub][0], v1 = s[sub][1], v2 = s[sub][2], v3 = s[sub][3];
            if (partial) {
              const int kb = jt * 64 + sub * 16 + quad * 4;
              v0 = (qrow >= kb)     ? v0 : -1.0e30f;
              v1 = (qrow >= kb + 1) ? v1 : -1.0e30f;
              v2 = (qrow >= kb + 2) ? v2 : -1.0e30f;
              v3 = (qrow >= kb + 3) ? v3 : -1.0e30f;
            }
            p0 = __expf(v0); p1 = __expf(v1); p2 = __expf(v2); p3 = __expf(v3);
          }
          l_acc += (p0 + p1) + (p2 + p3);
          uint2 dd;
          dd.x = __builtin_amdgcn_perm(__float_as_uint(p1), __float_as_uint(p0), 0x07060302u);
          dd.y = __builtin_amdgcn_perm(__float_as_uint(p3), __float_as_uint(p2), 0x07060302u);
          *(uint2*)&Pl[w][l15][sub * 16 + quad * 4] = dd;
        } else {
          uint2 zz; zz.x = 0u; zz.y = 0u;
          *(uint2*)&Pl[w][l15][sub * 16 + quad * 4] = zz;
        }
      }

      __builtin_amdgcn_s_setprio(1);
#pragma unroll
      for (int st = 0; st < 2; ++st) {
        if (st < steps) {
          bf16x8 pa = *(const bf16x8*)&Pl[w][l15][st * 32 + quad * 8];
#pragma unroll
          for (int sub = 0; sub < 4; ++sub) {
            bf16x8 vv = *(const bf16x8*)&Vt[sub * 16 + l15][st * 32 + quad * 8];
            o[sub] = __builtin_amdgcn_mfma_f32_16x16x32_bf16(pa, vv, o[sub], 0, 0, 0);
          }
        }
      }
      __builtin_amdgcn_s_setprio(0);
    }

    // epilogue: l lives at q=l15 per lane; reduce across quads, then
    // redistribute to the O row layout (q = quad*4+reg)
    float lt = l_acc;
    lt += __shfl_xor(lt, 16);
    lt += __shfl_xor(lt, 32);
    const float inv = 1.0f / lt;
#pragma unroll
    for (int reg = 0; reg < 4; ++reg) {
      const float invr = __shfl(inv, quad * 20 + reg);  // lane l15 = quad*4+reg
      const int sg = wq0 + quad * 4 + reg;
#pragma unroll
      for (int sub = 0; sub < 4; ++sub) {
        O[((size_t)(b * S_LEN + sg)) * DM + h * HD + sub * 16 + l15] = f2bf(o[sub][reg] * invr);
      }
    }
  }
}

extern "C" void kernel_launch(void* const* d_in, const int* in_sizes, int n_in,
                              void* d_out, int out_size, void* d_ws, size_t ws_size,
                              hipStream_t stream) {
  const float* x  = (const float*)d_in[0];  // fp32 [4,2048,1024]
  const float* wq = (const float*)d_in[1];  // fp32 [1024,1024]
  const float* wk = (const float*)d_in[2];
  const float* wv = (const float*)d_in[3];
  const float* wo = (const float*)d_in[4];

  unsigned short* Qb = (unsigned short*)d_ws;                 // 16 MB
  unsigned short* Kb = Qb + (size_t)M_ROWS * DM;              // 16 MB (Qb+z*16M)
  unsigned short* Vb = Kb + (size_t)M_ROWS * DM;              // 16 MB
  unsigned short* Xb = Vb + (size_t)M_ROWS * DM;              // 16 MB (alias Ob)
  unsigned short* Ob = Xb;
  (void)Kb; (void)Vb;

  // bf16 weight stash inside d_out (32 MB fp32 buffer; dead until final GEMM)
  unsigned short* Wstash = (unsigned short*)d_out;            // [3072][1024] bf16

  dim3 bb(256);
  dim3 gb(512);

  hipLaunchKernelGGL(cvt_bf16, dim3((M_ROWS * DM) / 2048), bb, 0, stream, x, Xb);
  hipLaunchKernelGGL(cvt_w3, dim3(3 * (DM * DM) / 2048), bb, 0, stream, wq, wk, wv, Wstash);
  // fused QKV as single GEMM: M=8192, N=3072 (z = e>>10 selects output slab)
  hipLaunchKernelGGL((gemm_bt<0>), dim3(M_ROWS / 256, 3 * DM / 128), gb, 0, stream,
                     Xb, Wstash, Qb, (float*)nullptr);
  hipLaunchKernelGGL(attn_mfma, dim3(64, 16), bb, 0, stream, Qb, Qb + (size_t)M_ROWS * DM,
                     Qb + 2 * (size_t)M_ROWS * DM, Ob);
  // wo -> bf16 into Qb (free after attention); then final projection
  hipLaunchKernelGGL(cvt_bf16, dim3((DM * DM) / 2048), bb, 0, stream, wo, Qb);
  hipLaunchKernelGGL((gemm_bt<1>), dim3(M_ROWS / 256, DM / 128), gb, 0, stream,
                     Ob, Qb, (unsigned short*)nullptr, (float*)d_out);
}

// Round 6
// 199.558 us; speedup vs baseline: 1.2721x; 1.2721x over previous
//
#include <hip/hip_runtime.h>
#include <hip/hip_bf16.h>
#include <math.h>

// Problem: MultiHeadSelfAttention  B=4, S=2048, D=1024, H=16, Hd=64
// fp32 in / fp32 out. bf16 scratch, fp32 accumulation.
// Round 15 (= R13 resubmit #2; R13/R14 benches died on infra pre-push:
// same wedged container, "connection closed while sending first message"):
//  - gemm: unchanged (R11 counted-vmcnt ring-3, verified).
//  - attn: mfma_32x32x16 with swapped QK^T (m214 structure).
//    Lane holds full q-row slice of S^T -> softmax lane-local; P packed to
//    bf16 dwords in-register; one shfl_xor(32) half-exchange + cndmask
//    selects build PV A-frags directly. NO P LDS round-trip (R11's 9.5M
//    bank conflicts were the Pl u16 writes; R12's b64 variant was worse:
//    even-banks-only). LDS = Ks+Vt = 18.4KB. Wave owns 32 q-rows; block =
//    128 rows; grid (bh=64, 16) with heavy-bx-first ordering.
// ws: Qb@0, Kb@16M, Vb@32M, Xb/Ob@48M (aliased). Wstash in d_out (dead
// until final GEMM); wo converted into Qb after attention frees it.

#define S_LEN 2048
#define DM    1024
#define NH    16
#define HD    64
#define M_ROWS 8192   // B * S

typedef __attribute__((ext_vector_type(8))) short bf16x8;
typedef __attribute__((ext_vector_type(4))) float f32x4;
typedef __attribute__((ext_vector_type(16))) float f32x16;

__device__ __forceinline__ float bf2f(unsigned short u) {
  union { unsigned int i; float f; } c; c.i = ((unsigned int)u) << 16; return c.f;
}
__device__ __forceinline__ unsigned short f2bf(float f) {
  unsigned int x = __float_as_uint(f);
  if ((x & 0x7fffffffu) > 0x7f800000u) return (unsigned short)0x7fc0u;  // NaN
  return (unsigned short)((x + 0x7fffu + ((x >> 16) & 1u)) >> 16);      // RNE
}
// async global->LDS, 16 B per lane; lds dest must be wave-uniform
__device__ __forceinline__ void gl_lds16(const unsigned short* g, unsigned short* l) {
  __builtin_amdgcn_global_load_lds(
      (const __attribute__((address_space(1))) unsigned int*)g,
      (__attribute__((address_space(3))) unsigned int*)l, 16, 0, 0);
}

#define FENCE() asm volatile("" ::: "memory")

// ---------------------------------------------------------------------------
// fp32 -> bf16 bulk convert (8 elems/thread)
// ---------------------------------------------------------------------------
__global__ __launch_bounds__(256) void cvt_bf16(const float* __restrict__ in,
                                                unsigned short* __restrict__ out) {
  const int i = blockIdx.x * 256 + threadIdx.x;
  float4 a = ((const float4*)in)[2 * i];
  float4 b = ((const float4*)in)[2 * i + 1];
  ushort4 r0, r1;
  r0.x = f2bf(a.x); r0.y = f2bf(a.y); r0.z = f2bf(a.z); r0.w = f2bf(a.w);
  r1.x = f2bf(b.x); r1.y = f2bf(b.y); r1.z = f2bf(b.z); r1.w = f2bf(b.w);
  ((ushort4*)out)[2 * i] = r0;
  ((ushort4*)out)[2 * i + 1] = r1;
}

// convert wq,wk,wv (1M fp32 each) into one contiguous bf16 stash [3072][1024]
__global__ __launch_bounds__(256) void cvt_w3(const float* __restrict__ w0,
                                              const float* __restrict__ w1,
                                              const float* __restrict__ w2,
                                              unsigned short* __restrict__ out) {
  const int idx = blockIdx.x;                 // 0..1535
  const int which = idx >> 9;
  const float* src = (which == 0) ? w0 : (which == 1) ? w1 : w2;
  unsigned short* dst = out + (size_t)which * (DM * DM);
  const int i = (idx & 511) * 256 + threadIdx.x;
  float4 a = ((const float4*)src)[2 * i];
  float4 b = ((const float4*)src)[2 * i + 1];
  ushort4 r0, r1;
  r0.x = f2bf(a.x); r0.y = f2bf(a.y); r0.z = f2bf(a.z); r0.w = f2bf(a.w);
  r1.x = f2bf(b.x); r1.y = f2bf(b.y); r1.z = f2bf(b.z); r1.w = f2bf(b.w);
  ((ushort4*)dst)[2 * i] = r0;
  ((ushort4*)dst)[2 * i + 1] = r1;
}

// ---------------------------------------------------------------------------
// MFMA GEMM, counted-vmcnt ring-3 global_load_lds pipeline (R11, verified).
// ---------------------------------------------------------------------------
template <int OUT_MODE>
__global__ __launch_bounds__(512, 4) void gemm_bt(const unsigned short* __restrict__ A,
                                                  const unsigned short* __restrict__ Wall,
                                                  unsigned short* __restrict__ outB,
                                                  float* __restrict__ outF) {
  __shared__ __align__(16) unsigned short As[3 * 8192];  // [buf][kgrp4][256][8]
  __shared__ __align__(16) unsigned short Bs[3 * 4096];  // [buf][kgrp4][128][8]
  const int m0 = blockIdx.x * 256;
  const int n0 = blockIdx.y * 128;
  const int tid = threadIdx.x;
  const int lane = tid & 63, w = tid >> 6;
  const int quad = lane >> 4, l15 = lane & 15;
  const int wrow = w >> 1, wcol = w & 1;    // compute mapping: 4M x 2N waves

  // staging map (independent of compute mapping)
  const int skg = w & 3, srq = w >> 2;
  const unsigned short* agA = A    + (size_t)(m0 + srq * 64 + lane) * DM + skg * 8;
  const unsigned short* bgB = Wall + (size_t)(n0 + srq * 64 + lane) * DM + skg * 8;
  const int lA0 = skg * 2048 + srq * 512;   // wave-uniform LDS elem offsets
  const int lA1 = lA0 + 1024;               // rows +128
  const int lB  = skg * 1024 + srq * 512;
  const int raA = quad * 2048 + (wrow * 64 + l15) * 8;  // frag-read bases
  const int raB = quad * 1024 + (wcol * 64 + l15) * 8;

  f32x4 acc[4][4];
#pragma unroll
  for (int i = 0; i < 4; ++i)
#pragma unroll
    for (int j = 0; j < 4; ++j) { acc[i][j].x = 0.f; acc[i][j].y = 0.f; acc[i][j].z = 0.f; acc[i][j].w = 0.f; }

#define STAGE3(T, SB) do {                                                   \
    const unsigned short* ap_ = agA + (size_t)(T) * 32;                      \
    gl_lds16(ap_,          &As[(SB) * 8192 + lA0]);                          \
    gl_lds16(ap_ + 131072, &As[(SB) * 8192 + lA1]);                          \
    gl_lds16(bgB + (size_t)(T) * 32, &Bs[(SB) * 4096 + lB]);                 \
  } while (0)

#define COMPUTE(CB) do {                                                     \
    bf16x8 af_[4], bq_[4];                                                   \
    _Pragma("unroll")                                                        \
    for (int mi = 0; mi < 4; ++mi)                                           \
      af_[mi] = *(const bf16x8*)&As[(CB) * 8192 + raA + mi * 128];           \
    _Pragma("unroll")                                                        \
    for (int ni = 0; ni < 4; ++ni)                                           \
      bq_[ni] = *(const bf16x8*)&Bs[(CB) * 4096 + raB + ni * 128];           \
    __builtin_amdgcn_s_setprio(1);                                           \
    _Pragma("unroll")                                                        \
    for (int mi = 0; mi < 4; ++mi)                                           \
      _Pragma("unroll")                                                      \
      for (int ni = 0; ni < 4; ++ni)                                         \
        acc[mi][ni] = __builtin_amdgcn_mfma_f32_16x16x32_bf16(af_[mi], bq_[ni], acc[mi][ni], 0, 0, 0); \
    __builtin_amdgcn_s_setprio(0);                                           \
  } while (0)

#define SUBSTEP(T, SB, CB) do {                                              \
    FENCE();                                                                 \
    STAGE3((T), (SB));                                                       \
    asm volatile("s_waitcnt vmcnt(6)" ::: "memory");                         \
    __builtin_amdgcn_s_barrier();                                            \
    FENCE();                                                                 \
    COMPUTE(CB);                                                             \
    FENCE();                                                                 \
    __builtin_amdgcn_s_barrier();                                            \
  } while (0)

  // prologue: tiles 0,1 into bufs 0,1 (ring fills; no wait yet)
  STAGE3(0, 0);
  STAGE3(1, 1);

  // main loop: 30 tiles, unrolled x3 for compile-time buffer indices
  for (int t = 0; t < 30; t += 3) {
    SUBSTEP(t + 2, 2, 0);
    SUBSTEP(t + 3, 0, 1);
    SUBSTEP(t + 4, 1, 2);
  }
  // drain: tile 30 in buf0 (tile 31 still in flight), then tile 31 in buf1
  asm volatile("s_waitcnt vmcnt(3)" ::: "memory");
  __builtin_amdgcn_s_barrier();
  FENCE();
  COMPUTE(0);
  FENCE();
  __builtin_amdgcn_s_barrier();
  asm volatile("s_waitcnt vmcnt(0)" ::: "memory");
  __builtin_amdgcn_s_barrier();
  FENCE();
  COMPUTE(1);

#undef SUBSTEP
#undef COMPUTE
#undef STAGE3

  const float oscale = (OUT_MODE == 0 && n0 < 1024) ? 0.125f : 1.0f;
#pragma unroll
  for (int mi = 0; mi < 4; ++mi) {
#pragma unroll
    for (int reg = 0; reg < 4; ++reg) {
      const int m = m0 + wrow * 64 + mi * 16 + quad * 4 + reg;
#pragma unroll
      for (int ni = 0; ni < 4; ++ni) {
        const int e = n0 + wcol * 64 + ni * 16 + l15;
        const float v = acc[mi][ni][reg];
        if (OUT_MODE == 0) {
          const int z = e >> 10;                   // 0:Q 1:K 2:V
          const int e10 = e & 1023;
          const int b = m >> 11, s = m & (S_LEN - 1);
          const int h = e10 >> 6, hd = e10 & 63;
          outB[(size_t)z * (M_ROWS * DM) +
               (((size_t)(b * NH + h)) * S_LEN + s) * HD + hd] = f2bf(v * oscale);
        } else {
          outF[(size_t)m * DM + e] = v;
        }
      }
    }
  }
}

// ---------------------------------------------------------------------------
// MFMA flash attention on 32x32x16, swapped QK^T, in-register softmax+P.
// Wave owns 32 q-rows (wq0 = bx*128 + w*32); block = 128 rows; KV tile 64.
// QK: S^T = mfma(K_frag, Q_frag): A row = k = lane&31 (+kb*32), B col = q =
// lane&31, k-dim t = (lane>>5)*8+e, chained over 4 dsteps (Hd=64).
// C layout (guide-verified): col=lane&31=q, row k = (r&3)+8*(r>>2)+4*hi.
// => lane holds 16 S values of ONE q-row. exp in fp32; pack pairs to bf16
// dwords pk[g][dw] (k = kb*32+g*8+4*hi+2*dw+{0,1}); shfl_xor(32) gives the
// partner half sk[]; PV A-frag (lane hi needs k = s*16+hi*8+0..7) built by
// compile-time selects:
//   f0 = hi? sk[g1,0] : pk[g0,0]   f1 = hi? sk[g1,1] : pk[g0,1]
//   f2 = hi? pk[g1,0] : sk[g0,0]   f3 = hi? pk[g1,1] : sk[g0,1]
//   (g0 = 2*(s&1), g1 = g0+1)  -- verified by element enumeration.
// Diagonal tile == wave's LAST tile (diag_jt = 2bx + (w>>1)); there
// kb==(w&1) is partial (mask l31 >= (r&3)+8*(r>>2)+4*hi), the other kb is
// full (w odd) or fully-masked->skipped (w even).
// l: fp32 per-lane sum + xor32; O scale redistributed via per-lane shfl.
// ---------------------------------------------------------------------------
__global__ __launch_bounds__(256, 4) void attn_mfma(const unsigned short* __restrict__ Q,
                                                    const unsigned short* __restrict__ K,
                                                    const unsigned short* __restrict__ V,
                                                    unsigned short* __restrict__ O) {
  __shared__ unsigned short Ks[64][72];
  __shared__ unsigned short Vt[64][72];
  const int bh = blockIdx.x;                 // 0..63
  const int bx = 15 - (int)blockIdx.y;       // heavy q-blocks dispatched first
  const int tid = threadIdx.x;
  const int w = tid >> 6, lane = tid & 63;
  const int l31 = lane & 31, hi = lane >> 5;
  const size_t base = (size_t)bh * S_LEN * HD;
  const int b = bh >> 4, h = bh & 15;
  const int wq0 = bx * 128 + w * 32;
  const int diag_jt = 2 * bx + (w >> 1);     // wave's last (and partial) tile
  const int jt_blk = 2 * bx + 1;             // block's last tile
  const int kr0 = tid >> 3, kc0 = (tid & 7) * 8;
  const int vs = (tid & 31) * 2, vh = (tid >> 5) * 8;

  // Q fragments (B-operand): lane (hi,q=l31) holds d = ds*16 + hi*8 + e
  bf16x8 qb[4];
#pragma unroll
  for (int ds = 0; ds < 4; ++ds)
    qb[ds] = *(const bf16x8*)(Q + base + (size_t)(wq0 + l31) * HD + ds * 16 + hi * 8);

  f32x16 o0, o1;
#pragma unroll
  for (int r = 0; r < 16; ++r) { o0[r] = 0.f; o1[r] = 0.f; }
  float l_acc = 0.f;

  for (int jt = 0; jt <= jt_blk; ++jt) {
    __syncthreads();
    {
      const unsigned short* kgp = K + base + (size_t)jt * 64 * HD;
      const unsigned short* vgp = V + base + (size_t)jt * 64 * HD;
      *(uint4*)&Ks[kr0][kc0]      = *(const uint4*)(kgp + kr0 * HD + kc0);
      *(uint4*)&Ks[kr0 + 32][kc0] = *(const uint4*)(kgp + (kr0 + 32) * HD + kc0);
      uint4 r0 = *(const uint4*)(vgp + (size_t)vs * HD + vh);
      uint4 r1 = *(const uint4*)(vgp + (size_t)(vs + 1) * HD + vh);
      const unsigned int* a0 = (const unsigned int*)&r0;
      const unsigned int* a1 = (const unsigned int*)&r1;
#pragma unroll
      for (int j = 0; j < 4; ++j) {
        *(unsigned int*)&Vt[vh + 2 * j][vs]     = __builtin_amdgcn_perm(a1[j], a0[j], 0x05040100u);
        *(unsigned int*)&Vt[vh + 2 * j + 1][vs] = __builtin_amdgcn_perm(a1[j], a0[j], 0x07060302u);
      }
    }
    __syncthreads();

    if (jt <= diag_jt) {                      // wave-uniform
      const bool diag = (jt == diag_jt);
      for (int kb = 0; kb < 2; ++kb) {
        const bool kb_zero = diag && ((w & 1) == 0) && (kb == 1);
        const bool kb_part = diag && (kb == (w & 1));
        if (kb_zero) continue;                // wave-uniform; no contribution

        f32x16 sa;
#pragma unroll
        for (int r = 0; r < 16; ++r) sa[r] = 0.f;
        __builtin_amdgcn_s_setprio(1);
#pragma unroll
        for (int ds = 0; ds < 4; ++ds) {
          bf16x8 kf = *(const bf16x8*)&Ks[kb * 32 + l31][ds * 16 + hi * 8];
          sa = __builtin_amdgcn_mfma_f32_32x32x16_bf16(kf, qb[ds], sa, 0, 0, 0);
        }
        __builtin_amdgcn_s_setprio(0);

        float p[16];
        if (kb_part) {
#pragma unroll
          for (int r = 0; r < 16; ++r) {
            const int krel = (r & 3) + 8 * (r >> 2) + 4 * hi;
            p[r] = __expf((l31 >= krel) ? sa[r] : -1.0e30f);
          }
        } else {
#pragma unroll
          for (int r = 0; r < 16; ++r) p[r] = __expf(sa[r]);
        }
        l_acc += (((p[0] + p[1]) + (p[2] + p[3])) + ((p[4] + p[5]) + (p[6] + p[7])))
               + (((p[8] + p[9]) + (p[10] + p[11])) + ((p[12] + p[13]) + (p[14] + p[15])));

        unsigned int pk[8], sk[8];
#pragma unroll
        for (int g = 0; g < 4; ++g) {
          pk[2 * g]     = __builtin_amdgcn_perm(__float_as_uint(p[4 * g + 1]), __float_as_uint(p[4 * g]),     0x07060302u);
          pk[2 * g + 1] = __builtin_amdgcn_perm(__float_as_uint(p[4 * g + 3]), __float_as_uint(p[4 * g + 2]), 0x07060302u);
        }
#pragma unroll
        for (int i = 0; i < 8; ++i) sk[i] = (unsigned int)__shfl_xor((int)pk[i], 32);

#pragma unroll
        for (int sl = 0; sl < 2; ++sl) {
          const int g0 = 2 * sl, g1 = 2 * sl + 1;
          union { unsigned int u[4]; bf16x8 v; } fa;
          fa.u[0] = hi ? sk[2 * g1]     : pk[2 * g0];
          fa.u[1] = hi ? sk[2 * g1 + 1] : pk[2 * g0 + 1];
          fa.u[2] = hi ? pk[2 * g1]     : sk[2 * g0];
          fa.u[3] = hi ? pk[2 * g1 + 1] : sk[2 * g0 + 1];
          const int s = kb * 2 + sl;
          bf16x8 v0 = *(const bf16x8*)&Vt[l31][s * 16 + hi * 8];
          bf16x8 v1 = *(const bf16x8*)&Vt[32 + l31][s * 16 + hi * 8];
          __builtin_amdgcn_s_setprio(1);
          o0 = __builtin_amdgcn_mfma_f32_32x32x16_bf16(fa.v, v0, o0, 0, 0, 0);
          o1 = __builtin_amdgcn_mfma_f32_32x32x16_bf16(fa.v, v1, o1, 0, 0, 0);
          __builtin_amdgcn_s_setprio(0);
        }
      }
    }
  }

  // epilogue: l total (xor32 joins the two k-halves), scale + write O
  const float lf = l_acc + __shfl_xor(l_acc, 32);
  const float inv = 1.0f / lf;
#pragma unroll
  for (int r = 0; r < 16; ++r) {
    const int qrel = (r & 3) + 8 * (r >> 2) + 4 * hi;
    const float invr = __shfl(inv, qrel);    // lane qrel holds l for q=wq0+qrel
    const size_t orow = (size_t)(b * S_LEN + wq0 + qrel) * DM + h * HD;
    O[orow + l31]      = f2bf(o0[r] * invr);
    O[orow + 32 + l31] = f2bf(o1[r] * invr);
  }
}

extern "C" void kernel_launch(void* const* d_in, const int* in_sizes, int n_in,
                              void* d_out, int out_size, void* d_ws, size_t ws_size,
                              hipStream_t stream) {
  const float* x  = (const float*)d_in[0];  // fp32 [4,2048,1024]
  const float* wq = (const float*)d_in[1];  // fp32 [1024,1024]
  const float* wk = (const float*)d_in[2];
  const float* wv = (const float*)d_in[3];
  const float* wo = (const float*)d_in[4];

  unsigned short* Qb = (unsigned short*)d_ws;                 // 16 MB
  unsigned short* Kb = Qb + (size_t)M_ROWS * DM;              // 16 MB (Qb+z*16M)
  unsigned short* Vb = Kb + (size_t)M_ROWS * DM;              // 16 MB
  unsigned short* Xb = Vb + (size_t)M_ROWS * DM;              // 16 MB (alias Ob)
  unsigned short* Ob = Xb;
  (void)Kb; (void)Vb;

  // bf16 weight stash inside d_out (32 MB fp32 buffer; dead until final GEMM)
  unsigned short* Wstash = (unsigned short*)d_out;            // [3072][1024] bf16

  dim3 bb(256);
  dim3 gb(512);

  hipLaunchKernelGGL(cvt_bf16, dim3((M_ROWS * DM) / 2048), bb, 0, stream, x, Xb);
  hipLaunchKernelGGL(cvt_w3, dim3(3 * (DM * DM) / 2048), bb, 0, stream, wq, wk, wv, Wstash);
  // fused QKV as single GEMM: M=8192, N=3072 (z = e>>10 selects output slab)
  hipLaunchKernelGGL((gemm_bt<0>), dim3(M_ROWS / 256, 3 * DM / 128), gb, 0, stream,
                     Xb, Wstash, Qb, (float*)nullptr);
  hipLaunchKernelGGL(attn_mfma, dim3(64, 16), bb, 0, stream, Qb, Qb + (size_t)M_ROWS * DM,
                     Qb + 2 * (size_t)M_ROWS * DM, Ob);
  // wo -> bf16 into Qb (free after attention); then final projection
  hipLaunchKernelGGL(cvt_bf16, dim3((DM * DM) / 2048), bb, 0, stream, wo, Qb);
  hipLaunchKernelGGL((gemm_bt<1>), dim3(M_ROWS / 256, DM / 128), gb, 0, stream,
                     Ob, Qb, (unsigned short*)nullptr, (float*)d_out);
}